// Round 19
// baseline (42.927 us; speedup 1.0000x reference)
//
#include <hip/hip_runtime.h>
#include <hip/hip_bf16.h>

// ---------------------------------------------------------------------------
// Metric_Loss: two fused (X X^T/128 -> exp(1+.) -> row-sum) passes + pair combine.
// B=8192, E=128, P=4096.  Output: scalar f32 = metric_tt + metric_st.
//
// Round 19: NHS=8 zero-tail at the hardware occupancy cap (2048 blocks =
// exactly 8/CU, 32 waves/CU) using R18's slim n-half body (peak live ~55-60
// VGPR, inside the 64 budget at 8 waves/EU). Distance map is perfectly
// uniform: t = h+1+8k covers t=1..64 exactly once, N=8 tiles per block;
// t=64 (h==7,k==7) zeroed via gate-multiplier for bm>=64; diag at h==3.
// Else identical to R18: MX-fp8 16x16x128, 2-phase counted-vmcnt, 16KB LDS,
// exp2 pre-scale sqrt(log2e/128), exact-f32 finalize.
//
// ws layout:
//   [0, 1MB)        Xt fp8    [8192][128]   scaled by sqrt(log2e/128)
//   [1MB, 2MB)      Xm fp8    [8192][128]   (mixed: even=text, odd=shape[r>>1])
//   [2MB, 2MB+64KB) R f32     [2][8192]     row sums of exp(1+D)
// ---------------------------------------------------------------------------

#define B_ROWS 8192
#define E_COLS 128
#define P_PAIRS 4096
#define NSTRIP 128              // 64-row strips
#define NHS 8                   // h-splits per strip (zero-tail: 2048 blocks)

using f32x4 = __attribute__((ext_vector_type(4))) float;
using i32x8 = __attribute__((ext_vector_type(8))) int;

// sqrt(log2(e)/128): MFMA yields acc = D*log2(e); exp(1+D) = e * exp2(acc)
#define BF_SCALE 0.106164482742544f
#define EULER    2.718281828459045f
#define SCALE1   0x7f            // E8M0 exponent 127 -> 2^0 (unit scale)

__device__ __forceinline__ unsigned pk4_fp8(float a, float b, float c, float d) {
    unsigned v = 0;
    v = __builtin_amdgcn_cvt_pk_fp8_f32(a * BF_SCALE, b * BF_SCALE, v, false);
    v = __builtin_amdgcn_cvt_pk_fp8_f32(c * BF_SCALE, d * BF_SCALE, v, true);
    return v;
}

__device__ __forceinline__ int lds_off(int row, int k0) {
    return (row << 7) + (k0 ^ ((row & 7) << 4));
}

// K=128 fragment from swizzled LDS: 32 contiguous fp8 at (row, k32).
__device__ __forceinline__ i32x8 load_frag32(const char* base, int row, int k32) {
    union { i32x8 v; int4 h[2]; } u;
    u.h[0] = *(const int4*)(base + lds_off(row, k32));
    u.h[1] = *(const int4*)(base + lds_off(row, k32 + 16));
    return u.v;
}

// Stage one 64x128 fp8 tile (8KB): 2 iters of 256 threads x 16B.
__device__ __forceinline__ void stage8k(const char* gsrc, char* ldst, int tid) {
#pragma unroll
    for (int it = 0; it < 2; ++it) {
        int L   = it * 4096 + tid * 16;
        int row = L >> 7;
        int cb  = L & 127;
        int src = (row << 7) + (cb ^ ((row & 7) << 4));
        __builtin_amdgcn_global_load_lds(
            (const __attribute__((address_space(1))) void*)(gsrc + src),
            (__attribute__((address_space(3))) void*)(ldst + L), 16, 0, 0);
    }
}

// --------------------------- conversion kernel -----------------------------
__global__ void convert_kernel(const float* __restrict__ text,
                               const float* __restrict__ shape,
                               unsigned* __restrict__ Xt,
                               unsigned* __restrict__ Xm,
                               float* __restrict__ R,
                               float* __restrict__ out) {
    int idx = blockIdx.x * blockDim.x + threadIdx.x;     // 4 elements per thread
    if (idx >= B_ROWS * E_COLS / 4) return;
    if (idx < 4096) {                                    // zero R (2*8192 f32)
        float4 z; z.x = z.y = z.z = z.w = 0.f;
        ((float4*)R)[idx] = z;
    }
    if (idx == 0) *out = 0.f;
    int e = idx * 4;
    float4 t = *(const float4*)(text + e);
    unsigned tp = pk4_fp8(t.x, t.y, t.z, t.w);
    Xt[idx] = tp;
    int row = e >> 7;
    if (row & 1) {
        int col = e & 127;
        float4 s = *(const float4*)(shape + (row >> 1) * E_COLS + col);
        Xm[idx] = pk4_fp8(s.x, s.y, s.z, s.w);
    } else {
        Xm[idx] = tp;
    }
}

// --------------------------- fused GEMM + rowsum (MX-fp8) ------------------
// Block = (strip bm in 0..127, split h in 0..7, layer l). Strip = 64 A-rows.
// h -> distances t = h+1 + 8k, k=0..7 (covers t=1..64 exactly once).
// h==3 adds the diagonal (from buf0). Tile (h==7,k==7) = t=64: valid pairs
// only for bm<64; for bm>=64 its contributions are multiplied by 0.
__launch_bounds__(256, 8)
__global__ void gemm_rowsum_kernel(const unsigned char* __restrict__ Xt,
                                   const unsigned char* __restrict__ Xm,
                                   float* __restrict__ R) {
    const int bm = blockIdx.x, h = blockIdx.y, l = blockIdx.z;
    const char* gX = (const char*)(l ? Xm : Xt);

    __shared__ __align__(16) char buf0[64 * 128];
    __shared__ __align__(16) char buf1[64 * 128];
    const int tid = threadIdx.x;

    const int t0 = h + 1;
    const int N  = 8;                            // uniform tile count
    const float gate7 = (h == 7 && bm >= 64) ? 0.f : 1.f;

    auto tf = [&](int i) -> int { return t0 + 8 * i; };

    // ---- prologue: stage A -> buf0, first B -> buf1 ----
    stage8k(gX + (size_t)bm * 8192, buf0, tid);
    stage8k(gX + (size_t)((bm + tf(0)) & 127) * 8192, buf1, tid);
    asm volatile("s_waitcnt vmcnt(2)" ::: "memory");     // A landed
    __builtin_amdgcn_s_barrier();

    const int lane = tid & 63;
    const int w  = tid >> 6;
    const int wr = w >> 1, wc = w & 1;
    const int rA0 = wr * 32 + (lane & 15);
    const int rB0 = wc * 32 + (lane & 15);
    const int k32 = (lane >> 4) * 32;            // byte offset of lane's K-slice

    // ---- hoist A fragments (2 m-frags, full K=128 each) ----
    i32x8 afr[2];
#pragma unroll
    for (int m = 0; m < 2; ++m)
        afr[m] = load_frag32(buf0, rA0 + m * 16, k32);

    float s_r[2][4] = {{0.f}};                   // persistent row partials [m][j]

    // ---- diagonal tile (h==3): B-frags also from buf0; rows only ----
    if (h == 3) {
#pragma unroll
        for (int n = 0; n < 2; ++n) {            // one n-half at a time
            i32x8 bfr = load_frag32(buf0, rB0 + n * 16, k32);
            f32x4 a0 = {}, a1 = {};
            a0 = __builtin_amdgcn_mfma_scale_f32_16x16x128_f8f6f4(
                afr[0], bfr, a0, 0, 0, 0, SCALE1, 0, SCALE1);
            a1 = __builtin_amdgcn_mfma_scale_f32_16x16x128_f8f6f4(
                afr[1], bfr, a1, 0, 0, 0, SCALE1, 0, SCALE1);
#pragma unroll
            for (int j = 0; j < 4; ++j) {
                s_r[0][j] += __builtin_amdgcn_exp2f(a0[j]);
                s_r[1][j] += __builtin_amdgcn_exp2f(a1[j]);
            }
        }
    }

    // ---- all buf0 reads done before it becomes a B buffer ----
    asm volatile("s_waitcnt lgkmcnt(0)" ::: "memory");
    __builtin_amdgcn_s_barrier();

    // ---- 2-phase pipelined loop over off-diagonal tiles ----
    int cur = 1;                                 // current B buffer: 1 -> buf1
    for (int idx = 0; idx < N; ++idx) {
        const bool hasnext = (idx + 1 < N);
        if (hasnext)
            stage8k(gX + (size_t)((bm + tf(idx + 1)) & 127) * 8192,
                    cur ? buf0 : buf1, tid);

        if (hasnext) { asm volatile("s_waitcnt vmcnt(2)" ::: "memory"); }
        else         { asm volatile("s_waitcnt vmcnt(0)" ::: "memory"); }
        __builtin_amdgcn_s_barrier();            // cur buffer staged (all waves)

        const char* lsrc = cur ? buf1 : buf0;
        const float g = (idx == 7) ? gate7 : 1.f;
        float s_c[2];
#pragma unroll
        for (int n = 0; n < 2; ++n) {            // one n-half at a time
            i32x8 bfr = load_frag32(lsrc, rB0 + n * 16, k32);
            f32x4 a0 = {}, a1 = {};
            __builtin_amdgcn_s_setprio(1);
            a0 = __builtin_amdgcn_mfma_scale_f32_16x16x128_f8f6f4(
                afr[0], bfr, a0, 0, 0, 0, SCALE1, 0, SCALE1);
            a1 = __builtin_amdgcn_mfma_scale_f32_16x16x128_f8f6f4(
                afr[1], bfr, a1, 0, 0, 0, SCALE1, 0, SCALE1);
            __builtin_amdgcn_s_setprio(0);
            float c = 0.f;
#pragma unroll
            for (int j = 0; j < 4; ++j) {
                float e0 = __builtin_amdgcn_exp2f(a0[j]) * g;
                float e1 = __builtin_amdgcn_exp2f(a1[j]) * g;
                s_r[0][j] += e0;
                s_r[1][j] += e1;
                c += e0 + e1;
            }
            s_c[n] = c;
        }

        asm volatile("s_waitcnt lgkmcnt(0)" ::: "memory");
        __builtin_amdgcn_s_barrier();            // cur reads done -> overwritable

        // ---- col sums -> shuffle + single atomic per wave ----
        const int bn = (bm + tf(idx)) & 127;
        float v0 = s_c[0] + __shfl_xor(s_c[0], 16, 64);
        v0 += __shfl_xor(v0, 32, 64);
        float v1 = s_c[1] + __shfl_xor(s_c[1], 16, 64);
        v1 += __shfl_xor(v1, 32, 64);
        if (lane < 32) {
            int nn   = lane >> 4;
            float vv = nn ? v1 : v0;
            int gcol = bn * 64 + wc * 32 + nn * 16 + (lane & 15);
            atomicAdd(&R[l * B_ROWS + gcol], EULER * vv);
        }
        cur ^= 1;
    }

    // ---- final row reduction (once per block) ----
#pragma unroll
    for (int m = 0; m < 2; ++m)
#pragma unroll
        for (int j = 0; j < 4; ++j) {
            float v = s_r[m][j];
            v += __shfl_xor(v, 1, 64);
            v += __shfl_xor(v, 2, 64);
            v += __shfl_xor(v, 4, 64);
            v += __shfl_xor(v, 8, 64);
            if ((lane & 15) == 0) {
                int grow = bm * 64 + wr * 32 + m * 16 + (lane >> 4) * 4 + j;
                atomicAdd(&R[l * B_ROWS + grow], EULER * v);
            }
        }
}

// --------------------------- finalize --------------------------------------
__global__ void finalize_kernel(const float* __restrict__ text,
                                const float* __restrict__ shape,
                                const float* __restrict__ R,
                                float* __restrict__ out) {
    const int tid = threadIdx.x;
    const int lane = tid & 63;
    const int w = tid >> 6;
    const float inv128 = 0.0078125f;
    float accum = 0.f;

    for (int task = blockIdx.x * 4 + w; task < 2 * P_PAIRS; task += 1024) {
        int l = task >> 12;
        int p = task & (P_PAIRS - 1);
        const float* a = text + (2 * p) * E_COLS;            // even row: text
        const float* b = l ? (shape + p * E_COLS) : (text + (2 * p + 1) * E_COLS);
        float2 av = *(const float2*)(a + lane * 2);
        float2 bv = *(const float2*)(b + lane * 2);
        float dii = av.x * av.x + av.y * av.y;
        float djj = bv.x * bv.x + bv.y * bv.y;
        float dij = av.x * bv.x + av.y * bv.y;
#pragma unroll
        for (int sh = 1; sh < 64; sh <<= 1) {
            dii += __shfl_xor(dii, sh, 64);
            djj += __shfl_xor(djj, sh, 64);
            dij += __shfl_xor(dij, sh, 64);
        }
        if (lane == 0) {
            float Dii = dii * inv128, Djj = djj * inv128, Dij = dij * inv128;
            float S = R[l * B_ROWS + 2 * p] + R[l * B_ROWS + 2 * p + 1]
                    - (__expf(1.f + Dii) + 2.f * __expf(1.f + Dij) + __expf(1.f + Djj));
            float J = __logf(S) - Dij;
            accum += 0.5f * J * J * (1.0f / (float)P_PAIRS);
        }
    }

    __shared__ float red[4];
    if (lane == 0) red[w] = accum;
    __syncthreads();
    if (tid == 0) atomicAdd(out, red[0] + red[1] + red[2] + red[3]);
}

// --------------------------- launch ----------------------------------------
extern "C" void kernel_launch(void* const* d_in, const int* in_sizes, int n_in,
                              void* d_out, int out_size, void* d_ws, size_t ws_size,
                              hipStream_t stream) {
    const float* text  = (const float*)d_in[0];
    const float* shape = (const float*)d_in[1];
    float* out = (float*)d_out;
    char* ws = (char*)d_ws;

    unsigned char* Xt = (unsigned char*)ws;
    unsigned char* Xm = (unsigned char*)(ws + 1u * 1024u * 1024u);
    float* R = (float*)(ws + 2u * 1024u * 1024u);

    convert_kernel<<<(B_ROWS * E_COLS / 4 + 255) / 256, 256, 0, stream>>>(
        text, shape, (unsigned*)Xt, (unsigned*)Xm, R, out);

    dim3 grid(NSTRIP, NHS, 2);                   // 128 strips x 8 splits x 2 layers
    gemm_rowsum_kernel<<<grid, 256, 0, stream>>>(Xt, Xm, R);

    finalize_kernel<<<256, 256, 0, stream>>>(text, shape, R, out);
}

// Round 20
// 39.396 us; speedup vs baseline: 1.0896x; 1.0896x over previous
//
#include <hip/hip_runtime.h>
#include <hip/hip_bf16.h>

// ---------------------------------------------------------------------------
// Metric_Loss: two fused (X X^T/128 -> exp(1+.) -> row-sum) passes + pair combine.
// B=8192, E=128, P=4096.  Output: scalar f32 = metric_tt + metric_st.
//
// Round 20 (FINAL = R18, measured best 39.6us): NHS=7 zero-tail (1792 blocks
// = exactly 7/CU, 28 waves/CU -- the measured occupancy optimum: 6/CU=40.5,
// 7/CU=39.6, 8/CU=42.9 regress). MX-fp8 16x16x128 MFMA (unit scales),
// 2-phase counted-vmcnt LDS pipeline, 16KB LDS, symmetry wrap-pairing
// (t=h+1+7k tiles t=1..63 exactly; diag at h==3; t=64 appended to h==0
// bm<64), exp2 pre-scale sqrt(log2e/128) -> 1 v_exp per element, n-half
// epilogue to fit the (256,7) VGPR budget, exact-f32 finalize for the
// sensitive Dij/diag terms.
//
// ws layout:
//   [0, 1MB)        Xt fp8    [8192][128]   scaled by sqrt(log2e/128)
//   [1MB, 2MB)      Xm fp8    [8192][128]   (mixed: even=text, odd=shape[r>>1])
//   [2MB, 2MB+64KB) R f32     [2][8192]     row sums of exp(1+D)
// ---------------------------------------------------------------------------

#define B_ROWS 8192
#define E_COLS 128
#define P_PAIRS 4096
#define NSTRIP 128              // 64-row strips
#define NHS 7                   // h-splits per strip (zero-tail: 1792 blocks)

using f32x4 = __attribute__((ext_vector_type(4))) float;
using i32x8 = __attribute__((ext_vector_type(8))) int;

// sqrt(log2(e)/128): MFMA yields acc = D*log2(e); exp(1+D) = e * exp2(acc)
#define BF_SCALE 0.106164482742544f
#define EULER    2.718281828459045f
#define SCALE1   0x7f            // E8M0 exponent 127 -> 2^0 (unit scale)

__device__ __forceinline__ unsigned pk4_fp8(float a, float b, float c, float d) {
    unsigned v = 0;
    v = __builtin_amdgcn_cvt_pk_fp8_f32(a * BF_SCALE, b * BF_SCALE, v, false);
    v = __builtin_amdgcn_cvt_pk_fp8_f32(c * BF_SCALE, d * BF_SCALE, v, true);
    return v;
}

__device__ __forceinline__ int lds_off(int row, int k0) {
    return (row << 7) + (k0 ^ ((row & 7) << 4));
}

// K=128 fragment from swizzled LDS: 32 contiguous fp8 at (row, k32).
__device__ __forceinline__ i32x8 load_frag32(const char* base, int row, int k32) {
    union { i32x8 v; int4 h[2]; } u;
    u.h[0] = *(const int4*)(base + lds_off(row, k32));
    u.h[1] = *(const int4*)(base + lds_off(row, k32 + 16));
    return u.v;
}

// Stage one 64x128 fp8 tile (8KB): 2 iters of 256 threads x 16B.
__device__ __forceinline__ void stage8k(const char* gsrc, char* ldst, int tid) {
#pragma unroll
    for (int it = 0; it < 2; ++it) {
        int L   = it * 4096 + tid * 16;
        int row = L >> 7;
        int cb  = L & 127;
        int src = (row << 7) + (cb ^ ((row & 7) << 4));
        __builtin_amdgcn_global_load_lds(
            (const __attribute__((address_space(1))) void*)(gsrc + src),
            (__attribute__((address_space(3))) void*)(ldst + L), 16, 0, 0);
    }
}

// --------------------------- conversion kernel -----------------------------
__global__ void convert_kernel(const float* __restrict__ text,
                               const float* __restrict__ shape,
                               unsigned* __restrict__ Xt,
                               unsigned* __restrict__ Xm,
                               float* __restrict__ R,
                               float* __restrict__ out) {
    int idx = blockIdx.x * blockDim.x + threadIdx.x;     // 4 elements per thread
    if (idx >= B_ROWS * E_COLS / 4) return;
    if (idx < 4096) {                                    // zero R (2*8192 f32)
        float4 z; z.x = z.y = z.z = z.w = 0.f;
        ((float4*)R)[idx] = z;
    }
    if (idx == 0) *out = 0.f;
    int e = idx * 4;
    float4 t = *(const float4*)(text + e);
    unsigned tp = pk4_fp8(t.x, t.y, t.z, t.w);
    Xt[idx] = tp;
    int row = e >> 7;
    if (row & 1) {
        int col = e & 127;
        float4 s = *(const float4*)(shape + (row >> 1) * E_COLS + col);
        Xm[idx] = pk4_fp8(s.x, s.y, s.z, s.w);
    } else {
        Xm[idx] = tp;
    }
}

// --------------------------- fused GEMM + rowsum (MX-fp8) ------------------
// Block = (strip bm in 0..127, split h in 0..6, layer l). Strip = 64 A-rows.
// h -> distances t = h+1 + 7k, k=0..8 (covers t=1..63 exactly once).
// h==3 adds the diagonal (from buf0); h==0, bm<64 appends t=64 as idx==9.
__launch_bounds__(256, 7)
__global__ void gemm_rowsum_kernel(const unsigned char* __restrict__ Xt,
                                   const unsigned char* __restrict__ Xm,
                                   float* __restrict__ R) {
    const int bm = blockIdx.x, h = blockIdx.y, l = blockIdx.z;
    const char* gX = (const char*)(l ? Xm : Xt);

    __shared__ __align__(16) char buf0[64 * 128];
    __shared__ __align__(16) char buf1[64 * 128];
    const int tid = threadIdx.x;

    const int t0 = h + 1;
    int N = 9;
    if (h == 0 && bm < 64) N = 10;               // idx==9 -> t=64

    auto tf = [&](int i) -> int { return (h == 0 && i == 9) ? 64 : (t0 + 7 * i); };

    // ---- prologue: stage A -> buf0, first B -> buf1 ----
    stage8k(gX + (size_t)bm * 8192, buf0, tid);
    stage8k(gX + (size_t)((bm + tf(0)) & 127) * 8192, buf1, tid);
    asm volatile("s_waitcnt vmcnt(2)" ::: "memory");     // A landed
    __builtin_amdgcn_s_barrier();

    const int lane = tid & 63;
    const int w  = tid >> 6;
    const int wr = w >> 1, wc = w & 1;
    const int rA0 = wr * 32 + (lane & 15);
    const int rB0 = wc * 32 + (lane & 15);
    const int k32 = (lane >> 4) * 32;            // byte offset of lane's K-slice

    // ---- hoist A fragments (2 m-frags, full K=128 each) ----
    i32x8 afr[2];
#pragma unroll
    for (int m = 0; m < 2; ++m)
        afr[m] = load_frag32(buf0, rA0 + m * 16, k32);

    float s_r[2][4] = {{0.f}};                   // persistent row partials [m][j]

    // ---- diagonal tile (h==3): B-frags also from buf0; rows only ----
    if (h == 3) {
#pragma unroll
        for (int n = 0; n < 2; ++n) {            // one n-half at a time
            i32x8 bfr = load_frag32(buf0, rB0 + n * 16, k32);
            f32x4 a0 = {}, a1 = {};
            a0 = __builtin_amdgcn_mfma_scale_f32_16x16x128_f8f6f4(
                afr[0], bfr, a0, 0, 0, 0, SCALE1, 0, SCALE1);
            a1 = __builtin_amdgcn_mfma_scale_f32_16x16x128_f8f6f4(
                afr[1], bfr, a1, 0, 0, 0, SCALE1, 0, SCALE1);
#pragma unroll
            for (int j = 0; j < 4; ++j) {
                s_r[0][j] += __builtin_amdgcn_exp2f(a0[j]);
                s_r[1][j] += __builtin_amdgcn_exp2f(a1[j]);
            }
        }
    }

    // ---- all buf0 reads done before it becomes a B buffer ----
    asm volatile("s_waitcnt lgkmcnt(0)" ::: "memory");
    __builtin_amdgcn_s_barrier();

    // ---- 2-phase pipelined loop over off-diagonal tiles ----
    int cur = 1;                                 // current B buffer: 1 -> buf1
    for (int idx = 0; idx < N; ++idx) {
        const bool hasnext = (idx + 1 < N);
        if (hasnext)
            stage8k(gX + (size_t)((bm + tf(idx + 1)) & 127) * 8192,
                    cur ? buf0 : buf1, tid);

        if (hasnext) { asm volatile("s_waitcnt vmcnt(2)" ::: "memory"); }
        else         { asm volatile("s_waitcnt vmcnt(0)" ::: "memory"); }
        __builtin_amdgcn_s_barrier();            // cur buffer staged (all waves)

        const char* lsrc = cur ? buf1 : buf0;
        float s_c[2];
#pragma unroll
        for (int n = 0; n < 2; ++n) {            // one n-half at a time
            i32x8 bfr = load_frag32(lsrc, rB0 + n * 16, k32);
            f32x4 a0 = {}, a1 = {};
            __builtin_amdgcn_s_setprio(1);
            a0 = __builtin_amdgcn_mfma_scale_f32_16x16x128_f8f6f4(
                afr[0], bfr, a0, 0, 0, 0, SCALE1, 0, SCALE1);
            a1 = __builtin_amdgcn_mfma_scale_f32_16x16x128_f8f6f4(
                afr[1], bfr, a1, 0, 0, 0, SCALE1, 0, SCALE1);
            __builtin_amdgcn_s_setprio(0);
            float c = 0.f;
#pragma unroll
            for (int j = 0; j < 4; ++j) {
                float e0 = __builtin_amdgcn_exp2f(a0[j]);
                float e1 = __builtin_amdgcn_exp2f(a1[j]);
                s_r[0][j] += e0;
                s_r[1][j] += e1;
                c += e0 + e1;
            }
            s_c[n] = c;
        }

        asm volatile("s_waitcnt lgkmcnt(0)" ::: "memory");
        __builtin_amdgcn_s_barrier();            // cur reads done -> overwritable

        // ---- col sums -> shuffle + single atomic per wave ----
        const int bn = (bm + tf(idx)) & 127;
        float v0 = s_c[0] + __shfl_xor(s_c[0], 16, 64);
        v0 += __shfl_xor(v0, 32, 64);
        float v1 = s_c[1] + __shfl_xor(s_c[1], 16, 64);
        v1 += __shfl_xor(v1, 32, 64);
        if (lane < 32) {
            int nn   = lane >> 4;
            float vv = nn ? v1 : v0;
            int gcol = bn * 64 + wc * 32 + nn * 16 + (lane & 15);
            atomicAdd(&R[l * B_ROWS + gcol], EULER * vv);
        }
        cur ^= 1;
    }

    // ---- final row reduction (once per block) ----
#pragma unroll
    for (int m = 0; m < 2; ++m)
#pragma unroll
        for (int j = 0; j < 4; ++j) {
            float v = s_r[m][j];
            v += __shfl_xor(v, 1, 64);
            v += __shfl_xor(v, 2, 64);
            v += __shfl_xor(v, 4, 64);
            v += __shfl_xor(v, 8, 64);
            if ((lane & 15) == 0) {
                int grow = bm * 64 + wr * 32 + m * 16 + (lane >> 4) * 4 + j;
                atomicAdd(&R[l * B_ROWS + grow], EULER * v);
            }
        }
}

// --------------------------- finalize --------------------------------------
__global__ void finalize_kernel(const float* __restrict__ text,
                                const float* __restrict__ shape,
                                const float* __restrict__ R,
                                float* __restrict__ out) {
    const int tid = threadIdx.x;
    const int lane = tid & 63;
    const int w = tid >> 6;
    const float inv128 = 0.0078125f;
    float accum = 0.f;

    for (int task = blockIdx.x * 4 + w; task < 2 * P_PAIRS; task += 1024) {
        int l = task >> 12;
        int p = task & (P_PAIRS - 1);
        const float* a = text + (2 * p) * E_COLS;            // even row: text
        const float* b = l ? (shape + p * E_COLS) : (text + (2 * p + 1) * E_COLS);
        float2 av = *(const float2*)(a + lane * 2);
        float2 bv = *(const float2*)(b + lane * 2);
        float dii = av.x * av.x + av.y * av.y;
        float djj = bv.x * bv.x + bv.y * bv.y;
        float dij = av.x * bv.x + av.y * bv.y;
#pragma unroll
        for (int sh = 1; sh < 64; sh <<= 1) {
            dii += __shfl_xor(dii, sh, 64);
            djj += __shfl_xor(djj, sh, 64);
            dij += __shfl_xor(dij, sh, 64);
        }
        if (lane == 0) {
            float Dii = dii * inv128, Djj = djj * inv128, Dij = dij * inv128;
            float S = R[l * B_ROWS + 2 * p] + R[l * B_ROWS + 2 * p + 1]
                    - (__expf(1.f + Dii) + 2.f * __expf(1.f + Dij) + __expf(1.f + Djj));
            float J = __logf(S) - Dij;
            accum += 0.5f * J * J * (1.0f / (float)P_PAIRS);
        }
    }

    __shared__ float red[4];
    if (lane == 0) red[w] = accum;
    __syncthreads();
    if (tid == 0) atomicAdd(out, red[0] + red[1] + red[2] + red[3]);
}

// --------------------------- launch ----------------------------------------
extern "C" void kernel_launch(void* const* d_in, const int* in_sizes, int n_in,
                              void* d_out, int out_size, void* d_ws, size_t ws_size,
                              hipStream_t stream) {
    const float* text  = (const float*)d_in[0];
    const float* shape = (const float*)d_in[1];
    float* out = (float*)d_out;
    char* ws = (char*)d_ws;

    unsigned char* Xt = (unsigned char*)ws;
    unsigned char* Xm = (unsigned char*)(ws + 1u * 1024u * 1024u);
    float* R = (float*)(ws + 2u * 1024u * 1024u);

    convert_kernel<<<(B_ROWS * E_COLS / 4 + 255) / 256, 256, 0, stream>>>(
        text, shape, (unsigned*)Xt, (unsigned*)Xm, R, out);

    dim3 grid(NSTRIP, NHS, 2);                   // 128 strips x 7 splits x 2 layers
    gemm_rowsum_kernel<<<grid, 256, 0, stream>>>(Xt, Xm, R);

    finalize_kernel<<<256, 256, 0, stream>>>(text, shape, R, out);
}